// Round 1
// baseline (117.651 us; speedup 1.0000x reference)
//
#include <hip/hip_runtime.h>

typedef unsigned short u16;
typedef __bf16 bf16x8 __attribute__((ext_vector_type(8)));
typedef float f32x4 __attribute__((ext_vector_type(4)));

#define AS1 __attribute__((address_space(1)))
#define AS3 __attribute__((address_space(3)))

// B=16, C=512, N=1024 (H=W=32)
#define BB 16
#define CC 512
#define NN 1024

__device__ __forceinline__ void async16(void* lds, const void* g) {
  __builtin_amdgcn_global_load_lds((AS1 void*)g, (AS3 void*)lds, 16, 0, 0);
}

__device__ __forceinline__ u16 f2bf(float f) {
  unsigned u = __float_as_uint(f);
  return (u16)((u + 0x7FFFu + ((u >> 16) & 1u)) >> 16);
}
__device__ __forceinline__ float bf2f(u16 h) {
  return __uint_as_float(((unsigned)h) << 16);
}

__device__ __forceinline__ float wredSum(float v) {
  for (int m = 32; m >= 1; m >>= 1) v += __shfl_xor(v, m, 64);
  return v;
}
__device__ __forceinline__ float wredMin(float v) {
  for (int m = 32; m >= 1; m >>= 1) v = fminf(v, __shfl_xor(v, m, 64));
  return v;
}
__device__ __forceinline__ float wredMax(float v) {
  for (int m = 32; m >= 1; m >>= 1) v = fmaxf(v, __shfl_xor(v, m, 64));
  return v;
}

// ---------------- Kernel 1: per-row mean + bf16 hi/lo split ----------------
__global__ __launch_bounds__(256) void k_prep(const float* __restrict__ x,
                                              u16* __restrict__ xhi,
                                              u16* __restrict__ xlo,
                                              float* __restrict__ mu) {
  size_t row = blockIdx.x;  // 0 .. B*C-1
  int t = threadIdx.x;
  const float4* xr = (const float4*)(x + row * NN);
  float4 v = xr[t];  // 256 threads * 4 = 1024
  float s = v.x + v.y + v.z + v.w;
  s = wredSum(s);
  __shared__ float wsum4[4];
  int lane = t & 63, w = t >> 6;
  if (lane == 0) wsum4[w] = s;
  __syncthreads();
  float tot = wsum4[0] + wsum4[1] + wsum4[2] + wsum4[3];
  if (t == 0) mu[row] = tot * (1.0f / (float)NN);

  ushort4 h, l;
  h.x = f2bf(v.x); l.x = f2bf(v.x - bf2f(h.x));
  h.y = f2bf(v.y); l.y = f2bf(v.y - bf2f(h.y));
  h.z = f2bf(v.z); l.z = f2bf(v.z - bf2f(h.z));
  h.w = f2bf(v.w); l.w = f2bf(v.w - bf2f(h.w));
  ((ushort4*)(xhi + row * NN))[t] = h;
  ((ushort4*)(xlo + row * NN))[t] = l;
}

// ---------------- Kernel 2: transpose x -> xt (bf16), per batch N x C ------
__global__ __launch_bounds__(256) void k_transpose(const float* __restrict__ x,
                                                   u16* __restrict__ xt) {
  int b = blockIdx.z;
  int c0 = blockIdx.y * 64;  // 8 tiles over C
  int n0 = blockIdx.x * 64;  // 16 tiles over N
  __shared__ u16 tile[64][65];
  int t = threadIdx.x;
  int col = t & 63;
  int r0 = t >> 6;  // 0..3
  const float* xb = x + ((size_t)b * CC + c0) * NN + n0;
#pragma unroll
  for (int k = 0; k < 16; ++k) {
    int r = r0 + k * 4;  // c-index within tile
    tile[r][col] = f2bf(xb[(size_t)r * NN + col]);
  }
  __syncthreads();
  u16* xtb = xt + ((size_t)b * NN + n0) * CC + c0;
#pragma unroll
  for (int k = 0; k < 16; ++k) {
    int r = r0 + k * 4;  // n-index within tile
    xtb[(size_t)r * CC + col] = tile[col][r];
  }
}

// ---------------- Kernel 3: energy = H*H^T + H*L^T + L*H^T (per batch) -----
// 128x128 tile, BK=32, 4 waves each computing 64x64 (4x4 frags of 16x16).
__global__ __launch_bounds__(256) void k_gemm1(const u16* __restrict__ xhi,
                                               const u16* __restrict__ xlo,
                                               float* __restrict__ energy) {
  int b = blockIdx.z;
  int by = blockIdx.y;  // c tile (0..3)
  int bx = blockIdx.x;  // d tile (0..3)
  __shared__ u16 lA[128 * 32];
  __shared__ u16 lB[128 * 32];
  int t = threadIdx.x;
  int lane = t & 63, w = t >> 6;
  int wr = (w >> 1) * 64, wc = (w & 1) * 64;
  int fr = lane & 15, fk = (lane >> 4) * 8;
  int srow = t >> 2;           // staging row (0..63)
  int scol = (t & 3) * 8;      // staging col (ushorts)

  const u16* hb = xhi + (size_t)b * CC * NN;
  const u16* lb = xlo + (size_t)b * CC * NN;
  const u16* As[3] = {hb, hb, lb};
  const u16* Bs[3] = {hb, lb, hb};

  f32x4 acc[4][4];
#pragma unroll
  for (int m = 0; m < 4; ++m)
#pragma unroll
    for (int n = 0; n < 4; ++n) acc[m][n] = (f32x4)(0.0f);

  for (int ph = 0; ph < 3; ++ph) {
    const u16* Ab = As[ph] + (size_t)(by * 128) * NN;
    const u16* Bb = Bs[ph] + (size_t)(bx * 128) * NN;
    for (int ks = 0; ks < NN; ks += 32) {
      async16(&lA[t * 8], Ab + (size_t)srow * NN + ks + scol);
      async16(&lA[2048 + t * 8], Ab + (size_t)(srow + 64) * NN + ks + scol);
      async16(&lB[t * 8], Bb + (size_t)srow * NN + ks + scol);
      async16(&lB[2048 + t * 8], Bb + (size_t)(srow + 64) * NN + ks + scol);
      __syncthreads();
      bf16x8 af[4], bf_[4];
#pragma unroll
      for (int m = 0; m < 4; ++m)
        af[m] = *(const bf16x8*)&lA[(wr + m * 16 + fr) * 32 + fk];
#pragma unroll
      for (int n = 0; n < 4; ++n)
        bf_[n] = *(const bf16x8*)&lB[(wc + n * 16 + fr) * 32 + fk];
#pragma unroll
      for (int m = 0; m < 4; ++m)
#pragma unroll
        for (int n = 0; n < 4; ++n)
          acc[m][n] = __builtin_amdgcn_mfma_f32_16x16x32_bf16(af[m], bf_[n], acc[m][n], 0, 0, 0);
      __syncthreads();
    }
  }

  float* Eb = energy + ((size_t)b * CC + by * 128) * CC + bx * 128;
  int orow = wr + (lane >> 4) * 4;
  int ocol = wc + (lane & 15);
#pragma unroll
  for (int m = 0; m < 4; ++m)
#pragma unroll
    for (int n = 0; n < 4; ++n)
#pragma unroll
      for (int r = 0; r < 4; ++r)
        Eb[(size_t)(orow + m * 16 + r) * CC + ocol + n * 16] = acc[m][n][r];
}

// ---------------- Kernel 4: dual softmax + blend -> att (bf16) -------------
// One wave per row c (512 entries over d). 4 waves/block.
__global__ __launch_bounds__(256) void k_att(const float* __restrict__ energy,
                                             const float* __restrict__ mu,
                                             const float* __restrict__ beta_p,
                                             u16* __restrict__ att) {
  int gw = blockIdx.x * 4 + (threadIdx.x >> 6);  // 0..8191
  int b = gw >> 9;
  int c = gw & 511;
  int lane = threadIdx.x & 63;
  const float* erow = energy + (size_t)gw * CC;
  const float* mub = mu + b * CC;
  float muc = mub[c];

  float e[8], mud[8];
#pragma unroll
  for (int j = 0; j < 8; ++j) {
    e[j] = erow[lane + j * 64];
    mud[j] = mub[lane + j * 64];
  }
  // softmax(energy_new) == exp(emin - e) / sum
  float emin = fminf(fminf(fminf(e[0], e[1]), fminf(e[2], e[3])),
                     fminf(fminf(e[4], e[5]), fminf(e[6], e[7])));
  emin = wredMin(emin);
  float pe[8], sum_e = 0.f;
#pragma unroll
  for (int j = 0; j < 8; ++j) { pe[j] = expf(emin - e[j]); sum_e += pe[j]; }
  sum_e = wredSum(sum_e);

  // sigma = (e - N*muc*mud) * (1/(N*sqrt(N)))
  float sg[8];
#pragma unroll
  for (int j = 0; j < 8; ++j)
    sg[j] = (e[j] - (float)NN * muc * mud[j]) * (1.0f / 32768.0f);
  float smax = fmaxf(fmaxf(fmaxf(sg[0], sg[1]), fmaxf(sg[2], sg[3])),
                     fmaxf(fmaxf(sg[4], sg[5]), fmaxf(sg[6], sg[7])));
  smax = wredMax(smax);
  float ps[8], sum_s = 0.f;
#pragma unroll
  for (int j = 0; j < 8; ++j) { ps[j] = expf(sg[j] - smax); sum_s += ps[j]; }
  sum_s = wredSum(sum_s);

  float bta = *beta_p;
  float we = (1.0f - bta) / sum_e;
  float wsc = bta / sum_s;
  u16* arow = att + (size_t)gw * CC;
#pragma unroll
  for (int j = 0; j < 8; ++j)
    arow[lane + j * 64] = f2bf(ps[j] * wsc + pe[j] * we);
}

// ---------------- Kernel 5: out = gamma * (att @ X) + x --------------------
// NT GEMM: out[c,n] = sum_d att[c,d] * xt[n,d].  M=512, N=1024, K=512.
__global__ __launch_bounds__(256) void k_gemm2(const u16* __restrict__ att,
                                               const u16* __restrict__ xt,
                                               const float* __restrict__ x,
                                               const float* __restrict__ gamma_p,
                                               float* __restrict__ out) {
  int b = blockIdx.z;
  int by = blockIdx.y;  // c tile (0..3)
  int bx = blockIdx.x;  // n tile (0..7)
  __shared__ u16 lA[128 * 32];
  __shared__ u16 lB[128 * 32];
  int t = threadIdx.x;
  int lane = t & 63, w = t >> 6;
  int wr = (w >> 1) * 64, wc = (w & 1) * 64;
  int fr = lane & 15, fk = (lane >> 4) * 8;
  int srow = t >> 2;
  int scol = (t & 3) * 8;

  const u16* Ab = att + ((size_t)b * CC + by * 128) * CC;
  const u16* Bb = xt + ((size_t)b * NN + bx * 128) * CC;

  f32x4 acc[4][4];
#pragma unroll
  for (int m = 0; m < 4; ++m)
#pragma unroll
    for (int n = 0; n < 4; ++n) acc[m][n] = (f32x4)(0.0f);

  for (int ks = 0; ks < CC; ks += 32) {
    async16(&lA[t * 8], Ab + (size_t)srow * CC + ks + scol);
    async16(&lA[2048 + t * 8], Ab + (size_t)(srow + 64) * CC + ks + scol);
    async16(&lB[t * 8], Bb + (size_t)srow * CC + ks + scol);
    async16(&lB[2048 + t * 8], Bb + (size_t)(srow + 64) * CC + ks + scol);
    __syncthreads();
    bf16x8 af[4], bf_[4];
#pragma unroll
    for (int m = 0; m < 4; ++m)
      af[m] = *(const bf16x8*)&lA[(wr + m * 16 + fr) * 32 + fk];
#pragma unroll
    for (int n = 0; n < 4; ++n)
      bf_[n] = *(const bf16x8*)&lB[(wc + n * 16 + fr) * 32 + fk];
#pragma unroll
    for (int m = 0; m < 4; ++m)
#pragma unroll
      for (int n = 0; n < 4; ++n)
        acc[m][n] = __builtin_amdgcn_mfma_f32_16x16x32_bf16(af[m], bf_[n], acc[m][n], 0, 0, 0);
    __syncthreads();
  }

  float g = *gamma_p;
  const float* xb = x + ((size_t)b * CC + by * 128) * NN + bx * 128;
  float* ob = out + ((size_t)b * CC + by * 128) * NN + bx * 128;
  int orow = wr + (lane >> 4) * 4;
  int ocol = wc + (lane & 15);
#pragma unroll
  for (int m = 0; m < 4; ++m)
#pragma unroll
    for (int n = 0; n < 4; ++n)
#pragma unroll
      for (int r = 0; r < 4; ++r) {
        size_t rr = (size_t)(orow + m * 16 + r) * NN + ocol + n * 16;
        ob[rr] = g * acc[m][n][r] + xb[rr];
      }
}

extern "C" void kernel_launch(void* const* d_in, const int* in_sizes, int n_in,
                              void* d_out, int out_size, void* d_ws, size_t ws_size,
                              hipStream_t stream) {
  const float* x = (const float*)d_in[0];
  const float* gamma = (const float*)d_in[1];
  const float* beta = (const float*)d_in[2];
  float* out = (float*)d_out;

  constexpr size_t BCN = (size_t)BB * CC * NN;  // 8,388,608
  constexpr size_t BCC = (size_t)BB * CC * CC;  // 4,194,304
  u16* xhi = (u16*)d_ws;
  u16* xlo = xhi + BCN;
  u16* xt = xlo + BCN;
  float* mu = (float*)(xt + BCN);
  float* energy = mu + (size_t)BB * CC;
  u16* att = (u16*)(energy + BCC);
  // total ws use: 3*16MB + 32KB + 16.78MB + 8.39MB ~= 75.5 MB

  k_prep<<<BB * CC, 256, 0, stream>>>(x, xhi, xlo, mu);
  k_transpose<<<dim3(16, 8, BB), 256, 0, stream>>>(x, xt);
  k_gemm1<<<dim3(4, 4, BB), 256, 0, stream>>>(xhi, xlo, energy);
  k_att<<<BB * CC / 4, 256, 0, stream>>>(energy, mu, beta, att);
  k_gemm2<<<dim3(8, 4, BB), 256, 0, stream>>>(att, xt, x, gamma, out);
}

// Round 2
// 81.032 us; speedup vs baseline: 1.4519x; 1.4519x over previous
//
#include <hip/hip_runtime.h>

typedef unsigned short u16;
typedef __bf16 bf16x8 __attribute__((ext_vector_type(8)));
typedef float f32x4 __attribute__((ext_vector_type(4)));

#define AS1 __attribute__((address_space(1)))
#define AS3 __attribute__((address_space(3)))

// B=16, C=512, N=1024 (H=W=32)
#define BB 16
#define CC 512
#define NN 1024

__device__ __forceinline__ void async16(void* lds, const void* g) {
  __builtin_amdgcn_global_load_lds((AS1 void*)g, (AS3 void*)lds, 16, 0, 0);
}

__device__ __forceinline__ u16 f2bf(float f) {
  unsigned u = __float_as_uint(f);
  return (u16)((u + 0x7FFFu + ((u >> 16) & 1u)) >> 16);
}
__device__ __forceinline__ float bf2f(u16 h) {
  return __uint_as_float(((unsigned)h) << 16);
}

__device__ __forceinline__ float wredSum(float v) {
  for (int m = 32; m >= 1; m >>= 1) v += __shfl_xor(v, m, 64);
  return v;
}
__device__ __forceinline__ float wredMin(float v) {
  for (int m = 32; m >= 1; m >>= 1) v = fminf(v, __shfl_xor(v, m, 64));
  return v;
}
__device__ __forceinline__ float wredMax(float v) {
  for (int m = 32; m >= 1; m >>= 1) v = fmaxf(v, __shfl_xor(v, m, 64));
  return v;
}

// Stage a 128-row x 64-col bf16 tile: LDS dest linear (global_load_lds
// constraint), global SOURCE pre-swizzled so that a ds_read with
// col8 ^ (row&7) lands on the right data (T2 / m173 pattern).
__device__ __forceinline__ void stage128x64(u16* lds, const u16* src, size_t ld, int t) {
#pragma unroll
  for (int i = 0; i < 4; ++i) {
    int f = i * 256 + t;
    int row = f >> 3;       // 0..127
    int c8 = f & 7;         // 16B slot within row
    int sc = (c8 ^ (row & 7)) * 8;  // swizzled source column (elems)
    async16(&lds[(size_t)f * 8], src + (size_t)row * ld + sc);
  }
}

// Read 8 contiguous logical k-elements [k0,k0+8) of `row` from swizzled tile.
__device__ __forceinline__ bf16x8 ldsfrag(const u16* lds, int row, int k0) {
  return *(const bf16x8*)&lds[row * 64 + (k0 ^ ((row & 7) * 8))];
}

// ---------------- Kernel 1: per-row mean + bf16 hi/lo split ----------------
__global__ __launch_bounds__(256) void k_prep(const float* __restrict__ x,
                                              u16* __restrict__ xhi,
                                              u16* __restrict__ xlo,
                                              float* __restrict__ mu) {
  size_t row = blockIdx.x;  // 0 .. B*C-1
  int t = threadIdx.x;
  const float4* xr = (const float4*)(x + row * NN);
  float4 v = xr[t];  // 256 threads * 4 = 1024
  float s = v.x + v.y + v.z + v.w;
  s = wredSum(s);
  __shared__ float wsum4[4];
  int lane = t & 63, w = t >> 6;
  if (lane == 0) wsum4[w] = s;
  __syncthreads();
  float tot = wsum4[0] + wsum4[1] + wsum4[2] + wsum4[3];
  if (t == 0) mu[row] = tot * (1.0f / (float)NN);

  ushort4 h, l;
  h.x = f2bf(v.x); l.x = f2bf(v.x - bf2f(h.x));
  h.y = f2bf(v.y); l.y = f2bf(v.y - bf2f(h.y));
  h.z = f2bf(v.z); l.z = f2bf(v.z - bf2f(h.z));
  h.w = f2bf(v.w); l.w = f2bf(v.w - bf2f(h.w));
  ((ushort4*)(xhi + row * NN))[t] = h;
  ((ushort4*)(xlo + row * NN))[t] = l;
}

// ---------------- Kernel 2: transpose xhi -> xt (bf16), per batch N x C ----
__global__ __launch_bounds__(256) void k_transpose(const u16* __restrict__ xhi,
                                                   u16* __restrict__ xt) {
  int b = blockIdx.z;
  int c0 = blockIdx.y * 64;  // 8 tiles over C
  int n0 = blockIdx.x * 64;  // 16 tiles over N
  __shared__ u16 tile[64][65];
  int t = threadIdx.x;
  int col = t & 63;
  int r0 = t >> 6;  // 0..3
  const u16* xb = xhi + ((size_t)b * CC + c0) * NN + n0;
#pragma unroll
  for (int k = 0; k < 16; ++k) {
    int r = r0 + k * 4;  // c-index within tile
    tile[r][col] = xb[(size_t)r * NN + col];
  }
  __syncthreads();
  u16* xtb = xt + ((size_t)b * NN + n0) * CC + c0;
#pragma unroll
  for (int k = 0; k < 16; ++k) {
    int r = r0 + k * 4;  // n-index within tile
    xtb[(size_t)r * CC + col] = tile[col][r];
  }
}

// ---------------- Kernel 3: P0 = H*H^T, P1 = H*L^T (per batch) -------------
// 512 blocks: 2/CU. z-role decoded from XCD-chunked 1-D grid: each XCD
// owns 2 complete batches (working set ~3MB <= 4MB L2).
__global__ __launch_bounds__(256, 2) void k_gemm1(const u16* __restrict__ xhi,
                                                  const u16* __restrict__ xlo,
                                                  float* __restrict__ P0,
                                                  float* __restrict__ P1) {
  int lid = blockIdx.x;                   // 0..511
  int sw = (lid & 7) * 64 + (lid >> 3);   // bijective XCD chunking
  int b = sw >> 5;                        // batch
  int r = sw & 31;
  int ph = r >> 4;                        // 0: H*H^T, 1: H*L^T
  int tile = r & 15;
  int by = tile >> 2, bx = tile & 3;

  __shared__ u16 lA[128 * 64];
  __shared__ u16 lB[128 * 64];
  int t = threadIdx.x;
  int lane = t & 63, w = t >> 6;
  int wr = (w >> 1) * 64, wc = (w & 1) * 64;
  int fr = lane & 15, fk = (lane >> 4) * 8;

  const u16* Ab = xhi + ((size_t)b * CC + by * 128) * NN;
  const u16* Bb = (ph ? xlo : xhi) + ((size_t)b * CC + bx * 128) * NN;
  float* P = ph ? P1 : P0;

  f32x4 acc[4][4];
#pragma unroll
  for (int m = 0; m < 4; ++m)
#pragma unroll
    for (int n = 0; n < 4; ++n) acc[m][n] = (f32x4)(0.0f);

  for (int ks = 0; ks < NN; ks += 64) {
    stage128x64(lA, Ab + ks, NN, t);
    stage128x64(lB, Bb + ks, NN, t);
    __syncthreads();
#pragma unroll
    for (int kk = 0; kk < 2; ++kk) {
      bf16x8 af[4], bg[4];
#pragma unroll
      for (int m = 0; m < 4; ++m) af[m] = ldsfrag(lA, wr + m * 16 + fr, kk * 32 + fk);
#pragma unroll
      for (int n = 0; n < 4; ++n) bg[n] = ldsfrag(lB, wc + n * 16 + fr, kk * 32 + fk);
#pragma unroll
      for (int m = 0; m < 4; ++m)
#pragma unroll
        for (int n = 0; n < 4; ++n)
          acc[m][n] = __builtin_amdgcn_mfma_f32_16x16x32_bf16(af[m], bg[n], acc[m][n], 0, 0, 0);
    }
    __syncthreads();
  }

  float* Pb = P + ((size_t)b * CC + by * 128) * CC + bx * 128;
  int orow = wr + (lane >> 4) * 4;
  int ocol = wc + (lane & 15);
#pragma unroll
  for (int m = 0; m < 4; ++m)
#pragma unroll
    for (int n = 0; n < 4; ++n)
#pragma unroll
      for (int q = 0; q < 4; ++q)
        Pb[(size_t)(orow + m * 16 + q) * CC + ocol + n * 16] = acc[m][n][q];
}

// ---------------- Kernel 4: e = P0 + P1 + P1^T; dual softmax -> att --------
// Block = 32 consecutive c-rows of one batch. P1^T term staged as a
// coalesced 32-column panel, transposed through LDS.
__global__ __launch_bounds__(256) void k_att(const float* __restrict__ P0,
                                             const float* __restrict__ P1,
                                             const float* __restrict__ mu,
                                             const float* __restrict__ beta_p,
                                             u16* __restrict__ att) {
  __shared__ float pt[32][513];  // [c_local][d], stride 513 -> conflict-free
  int blk = blockIdx.x;  // 0..255
  int b = blk >> 4;
  int c0 = (blk & 15) * 32;
  int t = threadIdx.x;
  const float* P0b = P0 + (size_t)b * CC * CC;
  const float* P1b = P1 + (size_t)b * CC * CC;

  // stage P1[0:512, c0:c0+32] transposed into pt
  int cb = (t & 7) * 4;
  for (int d = t >> 3; d < CC; d += 32) {
    float4 v = *(const float4*)&P1b[(size_t)d * CC + c0 + cb];
    pt[cb + 0][d] = v.x;
    pt[cb + 1][d] = v.y;
    pt[cb + 2][d] = v.z;
    pt[cb + 3][d] = v.w;
  }
  __syncthreads();

  int lane = t & 63, w = t >> 6;
  const float* mub = mu + b * CC;
  float bta = *beta_p;

  for (int i = 0; i < 8; ++i) {
    int cl = w * 8 + i;  // 0..31
    int c = c0 + cl;
    const float* r0 = P0b + (size_t)c * CC;
    const float* r1 = P1b + (size_t)c * CC;
    float muc = mub[c];

    float e[8], mud[8];
#pragma unroll
    for (int j = 0; j < 8; ++j) {
      int d = lane + j * 64;
      e[j] = r0[d] + r1[d] + pt[cl][d];
      mud[j] = mub[d];
    }
    // softmax(energy_new) == exp(emin - e) / sum
    float emin = fminf(fminf(fminf(e[0], e[1]), fminf(e[2], e[3])),
                       fminf(fminf(e[4], e[5]), fminf(e[6], e[7])));
    emin = wredMin(emin);
    float pe[8], sum_e = 0.f;
#pragma unroll
    for (int j = 0; j < 8; ++j) { pe[j] = expf(emin - e[j]); sum_e += pe[j]; }
    sum_e = wredSum(sum_e);

    // sigma = (e - N*muc*mud) * (1/(N*sqrt(N)))
    float sg[8];
#pragma unroll
    for (int j = 0; j < 8; ++j)
      sg[j] = (e[j] - (float)NN * muc * mud[j]) * (1.0f / 32768.0f);
    float smax = fmaxf(fmaxf(fmaxf(sg[0], sg[1]), fmaxf(sg[2], sg[3])),
                       fmaxf(fmaxf(sg[4], sg[5]), fmaxf(sg[6], sg[7])));
    smax = wredMax(smax);
    float ps[8], sum_s = 0.f;
#pragma unroll
    for (int j = 0; j < 8; ++j) { ps[j] = expf(sg[j] - smax); sum_s += ps[j]; }
    sum_s = wredSum(sum_s);

    float we = (1.0f - bta) / sum_e;
    float wsc = bta / sum_s;
    u16* arow = att + ((size_t)b * CC + c) * CC;
#pragma unroll
    for (int j = 0; j < 8; ++j)
      arow[lane + j * 64] = f2bf(ps[j] * wsc + pe[j] * we);
  }
}

// ---------------- Kernel 5: out = gamma * (att @ X) + x --------------------
// NT GEMM: out[c,n] = sum_d att[c,d] * xt[n,d].  M=512, N=1024, K=512.
__global__ __launch_bounds__(256, 2) void k_gemm2(const u16* __restrict__ att,
                                                  const u16* __restrict__ xt,
                                                  const float* __restrict__ x,
                                                  const float* __restrict__ gamma_p,
                                                  float* __restrict__ out) {
  int lid = blockIdx.x;                   // 0..511
  int sw = (lid & 7) * 64 + (lid >> 3);   // XCD chunking: 2 batches per XCD
  int b = sw >> 5;
  int r = sw & 31;
  int by = r >> 3;  // c tile (0..3)
  int bx = r & 7;   // n tile (0..7)

  __shared__ u16 lA[128 * 64];
  __shared__ u16 lB[128 * 64];
  int t = threadIdx.x;
  int lane = t & 63, w = t >> 6;
  int wr = (w >> 1) * 64, wc = (w & 1) * 64;
  int fr = lane & 15, fk = (lane >> 4) * 8;

  const u16* Ab = att + ((size_t)b * CC + by * 128) * CC;
  const u16* Bb = xt + ((size_t)b * NN + bx * 128) * CC;

  f32x4 acc[4][4];
#pragma unroll
  for (int m = 0; m < 4; ++m)
#pragma unroll
    for (int n = 0; n < 4; ++n) acc[m][n] = (f32x4)(0.0f);

  for (int ks = 0; ks < CC; ks += 64) {
    stage128x64(lA, Ab + ks, CC, t);
    stage128x64(lB, Bb + ks, CC, t);
    __syncthreads();
#pragma unroll
    for (int kk = 0; kk < 2; ++kk) {
      bf16x8 af[4], bg[4];
#pragma unroll
      for (int m = 0; m < 4; ++m) af[m] = ldsfrag(lA, wr + m * 16 + fr, kk * 32 + fk);
#pragma unroll
      for (int n = 0; n < 4; ++n) bg[n] = ldsfrag(lB, wc + n * 16 + fr, kk * 32 + fk);
#pragma unroll
      for (int m = 0; m < 4; ++m)
#pragma unroll
        for (int n = 0; n < 4; ++n)
          acc[m][n] = __builtin_amdgcn_mfma_f32_16x16x32_bf16(af[m], bg[n], acc[m][n], 0, 0, 0);
    }
    __syncthreads();
  }

  float g = *gamma_p;
  const float* xb = x + ((size_t)b * CC + by * 128) * NN + bx * 128;
  float* ob = out + ((size_t)b * CC + by * 128) * NN + bx * 128;
  int orow = wr + (lane >> 4) * 4;
  int ocol = wc + (lane & 15);
#pragma unroll
  for (int m = 0; m < 4; ++m)
#pragma unroll
    for (int n = 0; n < 4; ++n)
#pragma unroll
      for (int q = 0; q < 4; ++q) {
        size_t rr = (size_t)(orow + m * 16 + q) * NN + ocol + n * 16;
        ob[rr] = g * acc[m][n][q] + xb[rr];
      }
}

extern "C" void kernel_launch(void* const* d_in, const int* in_sizes, int n_in,
                              void* d_out, int out_size, void* d_ws, size_t ws_size,
                              hipStream_t stream) {
  const float* x = (const float*)d_in[0];
  const float* gamma = (const float*)d_in[1];
  const float* beta = (const float*)d_in[2];
  float* out = (float*)d_out;

  constexpr size_t BCN = (size_t)BB * CC * NN;  // 8,388,608
  constexpr size_t BCC = (size_t)BB * CC * CC;  // 4,194,304
  u16* xhi = (u16*)d_ws;           // 16.78 MB (dead after k_gemm1 -> reused as att)
  u16* xlo = xhi + BCN;            // 16.78 MB
  u16* xt = xlo + BCN;             // 16.78 MB
  float* mu = (float*)(xt + BCN);  // 32 KB
  float* P0 = mu + (size_t)BB * CC;  // 16.78 MB
  float* P1 = P0 + BCC;              // 16.78 MB
  u16* att = xhi;                    // alias: xhi dead once k_gemm1 completes
  // peak ws use ~= 84 MB

  k_prep<<<BB * CC, 256, 0, stream>>>(x, xhi, xlo, mu);
  k_transpose<<<dim3(16, 8, BB), 256, 0, stream>>>(xhi, xt);
  k_gemm1<<<512, 256, 0, stream>>>(xhi, xlo, P0, P1);
  k_att<<<256, 256, 0, stream>>>(P0, P1, mu, beta, att);
  k_gemm2<<<512, 256, 0, stream>>>(att, xt, x, gamma, out);
}

// Round 4
// 77.165 us; speedup vs baseline: 1.5247x; 1.0501x over previous
//
#include <hip/hip_runtime.h>

typedef unsigned short u16;
typedef __bf16 bf16x8 __attribute__((ext_vector_type(8)));
typedef float f32x4 __attribute__((ext_vector_type(4)));

#define AS1 __attribute__((address_space(1)))
#define AS3 __attribute__((address_space(3)))

// B=16, C=512, N=1024 (H=W=32)
#define BB 16
#define CC 512
#define NN 1024

__device__ __forceinline__ void async16(void* lds, const void* g) {
  __builtin_amdgcn_global_load_lds((AS1 void*)g, (AS3 void*)lds, 16, 0, 0);
}

__device__ __forceinline__ u16 f2bf(float f) {
  unsigned u = __float_as_uint(f);
  return (u16)((u + 0x7FFFu + ((u >> 16) & 1u)) >> 16);
}
__device__ __forceinline__ float bf2f(u16 h) {
  return __uint_as_float(((unsigned)h) << 16);
}

__device__ __forceinline__ float wredSum(float v) {
  for (int m = 32; m >= 1; m >>= 1) v += __shfl_xor(v, m, 64);
  return v;
}
__device__ __forceinline__ float wredMin(float v) {
  for (int m = 32; m >= 1; m >>= 1) v = fminf(v, __shfl_xor(v, m, 64));
  return v;
}
__device__ __forceinline__ float wredMax(float v) {
  for (int m = 32; m >= 1; m >>= 1) v = fmaxf(v, __shfl_xor(v, m, 64));
  return v;
}

// Stage a ROWS x 64-col bf16 tile: LDS dest linear (global_load_lds
// constraint), global SOURCE pre-swizzled so a ds_read with col8^(row&7)
// lands on the right data (T2 / m173 pattern).
template <int ROWS>
__device__ __forceinline__ void stageT(u16* lds, const u16* src, size_t ld, int t) {
#pragma unroll
  for (int i = 0; i < ROWS / 32; ++i) {
    int f = i * 256 + t;
    int row = f >> 3;                // 0..ROWS-1
    int c8 = f & 7;                  // 16B slot within row
    int sc = (c8 ^ (row & 7)) * 8;   // swizzled source column (elems)
    async16(&lds[(size_t)f * 8], src + (size_t)row * ld + sc);
  }
}

// Read 8 contiguous logical k-elements [k0,k0+8) of `row` from swizzled tile.
__device__ __forceinline__ bf16x8 ldsfrag(const u16* lds, int row, int k0) {
  return *(const bf16x8*)&lds[row * 64 + (k0 ^ ((row & 7) * 8))];
}

// ---------- Kernel 1: fused mean + hi/lo split + transpose(hi) -------------
// Block = 32 c-rows x full N of one batch. Grid 16x16.
__global__ __launch_bounds__(256) void k_prepT(const float* __restrict__ x,
                                               u16* __restrict__ xhi,
                                               u16* __restrict__ xlo,
                                               u16* __restrict__ xt,
                                               float* __restrict__ mu) {
  int b = blockIdx.y;
  int c0 = blockIdx.x * 32;
  int t = threadIdx.x;
  int row = t >> 3;   // 0..31 (c-local)
  int col4 = t & 7;   // float4 slot base
  __shared__ u16 tr[64][40];  // [n-local][c-local], pad to 40

  const float* xb = x + ((size_t)b * CC + c0) * NN;
  u16* hb = xhi + ((size_t)b * CC + c0) * NN;
  u16* lb = xlo + ((size_t)b * CC + c0) * NN;
  u16* tb = xt + (size_t)b * NN * CC + c0;

  float sum = 0.f;
  for (int nt = 0; nt < 16; ++nt) {
#pragma unroll
    for (int s = 0; s < 2; ++s) {
      int cc4 = col4 + 8 * s;  // 0..15
      size_t off = (size_t)row * NN + nt * 64 + cc4 * 4;
      float4 v = *(const float4*)&xb[off];
      sum += v.x + v.y + v.z + v.w;
      ushort4 h, l;
      h.x = f2bf(v.x); l.x = f2bf(v.x - bf2f(h.x));
      h.y = f2bf(v.y); l.y = f2bf(v.y - bf2f(h.y));
      h.z = f2bf(v.z); l.z = f2bf(v.z - bf2f(h.z));
      h.w = f2bf(v.w); l.w = f2bf(v.w - bf2f(h.w));
      *(ushort4*)&hb[off] = h;
      *(ushort4*)&lb[off] = l;
      tr[cc4 * 4 + 0][row] = h.x;
      tr[cc4 * 4 + 1][row] = h.y;
      tr[cc4 * 4 + 2][row] = h.z;
      tr[cc4 * 4 + 3][row] = h.w;
    }
    __syncthreads();
    // write xt rows: 64 n-rows x 32 u16 (two ushort4 per thread)
    int np = t >> 2, cs = t & 3;
#pragma unroll
    for (int s2 = 0; s2 < 2; ++s2) {
      int cl = cs * 4 + s2 * 16;
      *(ushort4*)&tb[(size_t)(nt * 64 + np) * CC + cl] = *(ushort4*)&tr[np][cl];
    }
    __syncthreads();
  }
  sum += __shfl_xor(sum, 1, 64);
  sum += __shfl_xor(sum, 2, 64);
  sum += __shfl_xor(sum, 4, 64);
  if ((t & 7) == 0) mu[(size_t)b * CC + c0 + row] = sum * (1.0f / (float)NN);
}

// ---------- Kernel 2: M = 0.5*H*H^T + H*L^T  (energy = M + M^T) ------------
// 128x64 output tile, dual accumulators, shared A-panel, 2-phase dbuf.
__global__ __launch_bounds__(256, 2) void k_gemm1(const u16* __restrict__ xhi,
                                                  const u16* __restrict__ xlo,
                                                  float* __restrict__ M) {
  int lid = blockIdx.x;                  // 0..511
  int sw = (lid & 7) * 64 + (lid >> 3);  // bijective XCD chunking: 2 batches/XCD
  int b = sw >> 5;
  int r = sw & 31;
  int by = r >> 3;  // 128-row tile (0..3)
  int bx = r & 7;   // 64-col tile (0..7)

  __shared__ u16 lds[2 * 16384];  // per buf: A[128*64]@0, Bh[64*64]@8192, Bl@12288
  int t = threadIdx.x;
  int lane = t & 63, w = t >> 6;
  int wr = (w >> 1) * 64;  // wave m-offset (2 halves)
  int wc = (w & 1) * 32;   // wave n-offset (2 halves)
  int fr = lane & 15, fk = (lane >> 4) * 8;

  const u16* Ab = xhi + ((size_t)b * CC + by * 128) * NN;
  const u16* Bh = xhi + ((size_t)b * CC + bx * 64) * NN;
  const u16* Bl = xlo + ((size_t)b * CC + bx * 64) * NN;

  f32x4 accH[4][2], accL[4][2];
#pragma unroll
  for (int m = 0; m < 4; ++m)
#pragma unroll
    for (int n = 0; n < 2; ++n) { accH[m][n] = (f32x4)(0.0f); accL[m][n] = (f32x4)(0.0f); }

  // prologue: stage tile 0 into buf 0
  stageT<128>(lds, Ab, NN, t);
  stageT<64>(lds + 8192, Bh, NN, t);
  stageT<64>(lds + 12288, Bl, NN, t);
  __syncthreads();

  int cur = 0;
  for (int ks = 0; ks < NN; ks += 64) {
    if (ks + 64 < NN) {
      u16* nb = lds + (cur ^ 1) * 16384;
      stageT<128>(nb, Ab + ks + 64, NN, t);
      stageT<64>(nb + 8192, Bh + ks + 64, NN, t);
      stageT<64>(nb + 12288, Bl + ks + 64, NN, t);
    }
    const u16* cb = lds + cur * 16384;
#pragma unroll
    for (int kk = 0; kk < 2; ++kk) {
      bf16x8 af[4], bh[2], bl[2];
#pragma unroll
      for (int m = 0; m < 4; ++m) af[m] = ldsfrag(cb, wr + m * 16 + fr, kk * 32 + fk);
#pragma unroll
      for (int n = 0; n < 2; ++n) {
        bh[n] = ldsfrag(cb + 8192, wc + n * 16 + fr, kk * 32 + fk);
        bl[n] = ldsfrag(cb + 12288, wc + n * 16 + fr, kk * 32 + fk);
      }
#pragma unroll
      for (int m = 0; m < 4; ++m)
#pragma unroll
        for (int n = 0; n < 2; ++n) {
          accH[m][n] = __builtin_amdgcn_mfma_f32_16x16x32_bf16(af[m], bh[n], accH[m][n], 0, 0, 0);
          accL[m][n] = __builtin_amdgcn_mfma_f32_16x16x32_bf16(af[m], bl[n], accL[m][n], 0, 0, 0);
        }
    }
    __syncthreads();  // drains next-tile loads (vmcnt 0) + barrier
    cur ^= 1;
  }

  float* Mb = M + ((size_t)b * CC + by * 128) * CC + bx * 64;
  int orow = wr + (lane >> 4) * 4;
  int ocol = wc + (lane & 15);
#pragma unroll
  for (int m = 0; m < 4; ++m)
#pragma unroll
    for (int n = 0; n < 2; ++n)
#pragma unroll
      for (int q = 0; q < 4; ++q)
        Mb[(size_t)(orow + m * 16 + q) * CC + ocol + n * 16] =
            0.5f * accH[m][n][q] + accL[m][n][q];
}

// ---------- Kernel 3: e = M + M^T; dual softmax; blend -> att (bf16) -------
__global__ __launch_bounds__(256) void k_att(const float* __restrict__ M,
                                             const float* __restrict__ mu,
                                             const float* __restrict__ beta_p,
                                             u16* __restrict__ att) {
  __shared__ float pt[32][513];  // [c_local][d] column panel of M
  int blk = blockIdx.x;  // 0..255
  int b = blk >> 4;
  int c0 = (blk & 15) * 32;
  int t = threadIdx.x;
  const float* Mb = M + (size_t)b * CC * CC;

  // stage M[0:512, c0:c0+32] transposed into pt
  int cb = (t & 7) * 4;
  for (int d = t >> 3; d < CC; d += 32) {
    float4 v = *(const float4*)&Mb[(size_t)d * CC + c0 + cb];
    pt[cb + 0][d] = v.x;
    pt[cb + 1][d] = v.y;
    pt[cb + 2][d] = v.z;
    pt[cb + 3][d] = v.w;
  }
  __syncthreads();

  int lane = t & 63, w = t >> 6;
  const float* mub = mu + b * CC;
  float bta = *beta_p;

  for (int i = 0; i < 8; ++i) {
    int cl = w * 8 + i;  // 0..31
    int c = c0 + cl;
    const float* r0 = Mb + (size_t)c * CC;
    float muc = mub[c];

    float e[8], mud[8];
#pragma unroll
    for (int j = 0; j < 8; ++j) {
      int d = lane + j * 64;
      e[j] = r0[d] + pt[cl][d];  // M[c,d] + M[d,c]
      mud[j] = mub[d];
    }
    // softmax(energy_new) == exp(emin - e) / sum
    float emin = fminf(fminf(fminf(e[0], e[1]), fminf(e[2], e[3])),
                       fminf(fminf(e[4], e[5]), fminf(e[6], e[7])));
    emin = wredMin(emin);
    float pe[8], sum_e = 0.f;
#pragma unroll
    for (int j = 0; j < 8; ++j) { pe[j] = expf(emin - e[j]); sum_e += pe[j]; }
    sum_e = wredSum(sum_e);

    // sigma = (e - N*muc*mud) * (1/(N*sqrt(N)))
    float sg[8];
#pragma unroll
    for (int j = 0; j < 8; ++j)
      sg[j] = (e[j] - (float)NN * muc * mud[j]) * (1.0f / 32768.0f);
    float smax = fmaxf(fmaxf(fmaxf(sg[0], sg[1]), fmaxf(sg[2], sg[3])),
                       fmaxf(fmaxf(sg[4], sg[5]), fmaxf(sg[6], sg[7])));
    smax = wredMax(smax);
    float ps[8], sum_s = 0.f;
#pragma unroll
    for (int j = 0; j < 8; ++j) { ps[j] = expf(sg[j] - smax); sum_s += ps[j]; }
    sum_s = wredSum(sum_s);

    float we = (1.0f - bta) / sum_e;
    float wsc = bta / sum_s;
    u16* arow = att + ((size_t)b * CC + c) * CC;
#pragma unroll
    for (int j = 0; j < 8; ++j)
      arow[lane + j * 64] = f2bf(ps[j] * wsc + pe[j] * we);
  }
}

// ---------- Kernel 4: out = gamma * (att @ X) + x --------------------------
// NT GEMM: out[c,n] = sum_d att[c,d] * xt[n,d]; 2-phase dbuf pipeline.
__global__ __launch_bounds__(256, 2) void k_gemm2(const u16* __restrict__ att,
                                                  const u16* __restrict__ xt,
                                                  const float* __restrict__ x,
                                                  const float* __restrict__ gamma_p,
                                                  float* __restrict__ out) {
  int lid = blockIdx.x;                  // 0..511
  int sw = (lid & 7) * 64 + (lid >> 3);  // XCD chunking: 2 batches/XCD
  int b = sw >> 5;
  int r = sw & 31;
  int by = r >> 3;  // c tile (0..3)
  int bx = r & 7;   // n tile (0..7)

  __shared__ u16 lds[2 * 16384];  // per buf: A[128*64]@0, B[128*64]@8192
  int t = threadIdx.x;
  int lane = t & 63, w = t >> 6;
  int wr = (w >> 1) * 64, wc = (w & 1) * 64;
  int fr = lane & 15, fk = (lane >> 4) * 8;

  const u16* Ab = att + ((size_t)b * CC + by * 128) * CC;
  const u16* Bb = xt + ((size_t)b * NN + bx * 128) * CC;

  f32x4 acc[4][4];
#pragma unroll
  for (int m = 0; m < 4; ++m)
#pragma unroll
    for (int n = 0; n < 4; ++n) acc[m][n] = (f32x4)(0.0f);

  stageT<128>(lds, Ab, CC, t);
  stageT<128>(lds + 8192, Bb, CC, t);
  __syncthreads();

  int cur = 0;
  for (int ks = 0; ks < CC; ks += 64) {
    if (ks + 64 < CC) {
      u16* nb = lds + (cur ^ 1) * 16384;
      stageT<128>(nb, Ab + ks + 64, CC, t);
      stageT<128>(nb + 8192, Bb + ks + 64, CC, t);
    }
    const u16* cb = lds + cur * 16384;
#pragma unroll
    for (int kk = 0; kk < 2; ++kk) {
      bf16x8 af[4], bg[4];
#pragma unroll
      for (int m = 0; m < 4; ++m) af[m] = ldsfrag(cb, wr + m * 16 + fr, kk * 32 + fk);
#pragma unroll
      for (int n = 0; n < 4; ++n) bg[n] = ldsfrag(cb + 8192, wc + n * 16 + fr, kk * 32 + fk);
#pragma unroll
      for (int m = 0; m < 4; ++m)
#pragma unroll
        for (int n = 0; n < 4; ++n)
          acc[m][n] = __builtin_amdgcn_mfma_f32_16x16x32_bf16(af[m], bg[n], acc[m][n], 0, 0, 0);
    }
    __syncthreads();
    cur ^= 1;
  }

  float g = *gamma_p;
  const float* xb = x + ((size_t)b * CC + by * 128) * NN + bx * 128;
  float* ob = out + ((size_t)b * CC + by * 128) * NN + bx * 128;
  int orow = wr + (lane >> 4) * 4;
  int ocol = wc + (lane & 15);
#pragma unroll
  for (int m = 0; m < 4; ++m)
#pragma unroll
    for (int n = 0; n < 4; ++n)
#pragma unroll
      for (int q = 0; q < 4; ++q) {
        size_t rr = (size_t)(orow + m * 16 + q) * NN + ocol + n * 16;
        ob[rr] = g * acc[m][n][q] + xb[rr];
      }
}

extern "C" void kernel_launch(void* const* d_in, const int* in_sizes, int n_in,
                              void* d_out, int out_size, void* d_ws, size_t ws_size,
                              hipStream_t stream) {
  const float* x = (const float*)d_in[0];
  const float* gamma = (const float*)d_in[1];
  const float* beta = (const float*)d_in[2];
  float* out = (float*)d_out;

  constexpr size_t BCN = (size_t)BB * CC * NN;  // 8,388,608
  constexpr size_t BCC = (size_t)BB * CC * CC;  // 4,194,304
  u16* xhi = (u16*)d_ws;             // 16.78 MB (dead after k_gemm1 -> att)
  u16* xlo = xhi + BCN;              // 16.78 MB
  u16* xt = xlo + BCN;               // 16.78 MB
  float* mu = (float*)(xt + BCN);    // 32 KB
  float* M = mu + (size_t)BB * CC;   // 16.78 MB
  u16* att = xhi;                    // alias: xhi dead after k_gemm1
  // peak ws use ~= 67.2 MB

  k_prepT<<<dim3(16, BB), 256, 0, stream>>>(x, xhi, xlo, xt, mu);
  k_gemm1<<<512, 256, 0, stream>>>(xhi, xlo, M);
  k_att<<<256, 256, 0, stream>>>(M, mu, beta, att);
  k_gemm2<<<512, 256, 0, stream>>>(att, xt, x, gamma, out);
}

// Round 5
// 70.797 us; speedup vs baseline: 1.6618x; 1.0899x over previous
//
#include <hip/hip_runtime.h>

typedef unsigned short u16;
typedef __bf16 bf16x8 __attribute__((ext_vector_type(8)));
typedef float f32x4 __attribute__((ext_vector_type(4)));

#define AS1 __attribute__((address_space(1)))
#define AS3 __attribute__((address_space(3)))

// B=16, C=512, N=1024 (H=W=32)
#define BB 16
#define CC 512
#define NN 1024

__device__ __forceinline__ void async16(void* lds, const void* g) {
  __builtin_amdgcn_global_load_lds((AS1 void*)g, (AS3 void*)lds, 16, 0, 0);
}

__device__ __forceinline__ u16 f2bf(float f) {
  unsigned u = __float_as_uint(f);
  return (u16)((u + 0x7FFFu + ((u >> 16) & 1u)) >> 16);
}
__device__ __forceinline__ float bf2f(u16 h) {
  return __uint_as_float(((unsigned)h) << 16);
}

__device__ __forceinline__ float wredSum(float v) {
  for (int m = 32; m >= 1; m >>= 1) v += __shfl_xor(v, m, 64);
  return v;
}
__device__ __forceinline__ float wredMin(float v) {
  for (int m = 32; m >= 1; m >>= 1) v = fminf(v, __shfl_xor(v, m, 64));
  return v;
}
__device__ __forceinline__ float wredMax(float v) {
  for (int m = 32; m >= 1; m >>= 1) v = fmaxf(v, __shfl_xor(v, m, 64));
  return v;
}

// Stage a ROWS x 64-col bf16 tile with T threads: LDS dest linear
// (global_load_lds constraint), global SOURCE pre-swizzled so a ds_read with
// col8^(row&7) lands on the right data (T2 / m173 pattern).
template <int ROWS, int T>
__device__ __forceinline__ void stageT(u16* lds, const u16* src, size_t ld, int t) {
#pragma unroll
  for (int i = 0; i < ROWS * 8 / T; ++i) {
    int f = i * T + t;
    int row = f >> 3;                // 0..ROWS-1
    int c8 = f & 7;                  // 16B slot within row
    int sc = (c8 ^ (row & 7)) * 8;   // swizzled source column (elems)
    async16(&lds[(size_t)f * 8], src + (size_t)row * ld + sc);
  }
}

// Read 8 contiguous logical k-elements [k0,k0+8) of `row` from swizzled tile.
__device__ __forceinline__ bf16x8 ldsfrag(const u16* lds, int row, int k0) {
  return *(const bf16x8*)&lds[row * 64 + (k0 ^ ((row & 7) * 8))];
}

// ---------- Kernel 1: fused mean + hi/lo split + transpose(hi) -------------
// Block = 32 c-rows x full N of one batch. 1-D grid 256, XCD-chunked so
// batch b lands on XCD b>>1 (matches gemm1's mapping -> L2-warm xhi/xlo).
__global__ __launch_bounds__(256) void k_prepT(const float* __restrict__ x,
                                               u16* __restrict__ xhi,
                                               u16* __restrict__ xlo,
                                               u16* __restrict__ xt,
                                               float* __restrict__ mu) {
  int lid = blockIdx.x;                  // 0..255
  int sw = (lid & 7) * 32 + (lid >> 3);  // bijective XCD chunking
  int b = sw >> 4;
  int c0 = (sw & 15) * 32;
  int t = threadIdx.x;
  int row = t >> 3;   // 0..31 (c-local)
  int col4 = t & 7;   // float4 slot base
  // tr[buf][n-local][c-local-swizzled]: store col' = c ^ ((n>>2 & 7)*4)
  __shared__ u16 tr[2][64][40];

  const float* xb = x + ((size_t)b * CC + c0) * NN;
  u16* hb = xhi + ((size_t)b * CC + c0) * NN;
  u16* lb = xlo + ((size_t)b * CC + c0) * NN;
  u16* tb = xt + (size_t)b * NN * CC + c0;

  float sum = 0.f;
  int wkey = col4 * 4;  // write swizzle key: ((cc4&7)*4) == col4*4 for both s
  for (int nt = 0; nt < 16; ++nt) {
    u16(*tbuf)[40] = tr[nt & 1];
#pragma unroll
    for (int s = 0; s < 2; ++s) {
      int cc4 = col4 + 8 * s;  // n-block 0..15
      size_t off = (size_t)row * NN + nt * 64 + cc4 * 4;
      float4 v = *(const float4*)&xb[off];
      sum += v.x + v.y + v.z + v.w;
      ushort4 h, l;
      h.x = f2bf(v.x); l.x = f2bf(v.x - bf2f(h.x));
      h.y = f2bf(v.y); l.y = f2bf(v.y - bf2f(h.y));
      h.z = f2bf(v.z); l.z = f2bf(v.z - bf2f(h.z));
      h.w = f2bf(v.w); l.w = f2bf(v.w - bf2f(h.w));
      *(ushort4*)&hb[off] = h;
      *(ushort4*)&lb[off] = l;
      int csw = row ^ wkey;
      tbuf[cc4 * 4 + 0][csw] = h.x;
      tbuf[cc4 * 4 + 1][csw] = h.y;
      tbuf[cc4 * 4 + 2][csw] = h.z;
      tbuf[cc4 * 4 + 3][csw] = h.w;
    }
    __syncthreads();
    // write xt rows: 64 n-rows x 32 u16 (two ushort4 per thread), un-swizzle
    int np = t >> 2, cs = t & 3;
    int rkey = ((np >> 2) & 7) * 4;
#pragma unroll
    for (int s2 = 0; s2 < 2; ++s2) {
      int cl = cs * 4 + s2 * 16;
      *(ushort4*)&tb[(size_t)(nt * 64 + np) * CC + cl] =
          *(ushort4*)&tbuf[np][cl ^ rkey];
    }
    // no 2nd barrier: buffer nt&1 is only overwritten at nt+2, after the
    // barrier inside iteration nt+1.
  }
  sum += __shfl_xor(sum, 1, 64);
  sum += __shfl_xor(sum, 2, 64);
  sum += __shfl_xor(sum, 4, 64);
  if ((t & 7) == 0) mu[(size_t)b * CC + c0 + row] = sum * (1.0f / (float)NN);
}

// ---------- Kernel 2: M = 0.5*H*H^T + H*L^T  (energy = M + M^T) ------------
// 128x128 output tile, dual accumulators, 512 threads (8 waves 2x4),
// 96 KB LDS double-buffer, 2-phase prefetch. Intensity 87 FLOP/B.
__global__ __launch_bounds__(512, 2) void k_gemm1(const u16* __restrict__ xhi,
                                                  const u16* __restrict__ xlo,
                                                  float* __restrict__ M) {
  int lid = blockIdx.x;                  // 0..255
  int sw = (lid & 7) * 32 + (lid >> 3);  // XCD chunking: 2 batches/XCD
  int b = sw >> 4;
  int r = sw & 15;
  int by = r >> 2;  // 128-row tile (0..3)
  int bx = r & 3;   // 128-col tile (0..3)

  __shared__ u16 lds[2 * 24576];  // per buf: A[128*64]@0, Bh@8192, Bl@16384
  int t = threadIdx.x;
  int lane = t & 63, w = t >> 6;
  int wr = (w >> 2) * 64;  // wave m-offset (2 groups)
  int wc = (w & 3) * 32;   // wave n-offset (4 groups)
  int fr = lane & 15, fk = (lane >> 4) * 8;

  const u16* Ab = xhi + ((size_t)b * CC + by * 128) * NN;
  const u16* Bh = xhi + ((size_t)b * CC + bx * 128) * NN;
  const u16* Bl = xlo + ((size_t)b * CC + bx * 128) * NN;

  f32x4 accH[4][2], accL[4][2];
#pragma unroll
  for (int m = 0; m < 4; ++m)
#pragma unroll
    for (int n = 0; n < 2; ++n) { accH[m][n] = (f32x4)(0.0f); accL[m][n] = (f32x4)(0.0f); }

  stageT<128, 512>(lds, Ab, NN, t);
  stageT<128, 512>(lds + 8192, Bh, NN, t);
  stageT<128, 512>(lds + 16384, Bl, NN, t);
  __syncthreads();

  int cur = 0;
  for (int ks = 0; ks < NN; ks += 64) {
    if (ks + 64 < NN) {
      u16* nb = lds + (cur ^ 1) * 24576;
      stageT<128, 512>(nb, Ab + ks + 64, NN, t);
      stageT<128, 512>(nb + 8192, Bh + ks + 64, NN, t);
      stageT<128, 512>(nb + 16384, Bl + ks + 64, NN, t);
    }
    const u16* cb = lds + cur * 24576;
#pragma unroll
    for (int kk = 0; kk < 2; ++kk) {
      bf16x8 af[4], bh[2], bl[2];
#pragma unroll
      for (int m = 0; m < 4; ++m) af[m] = ldsfrag(cb, wr + m * 16 + fr, kk * 32 + fk);
#pragma unroll
      for (int n = 0; n < 2; ++n) {
        bh[n] = ldsfrag(cb + 8192, wc + n * 16 + fr, kk * 32 + fk);
        bl[n] = ldsfrag(cb + 16384, wc + n * 16 + fr, kk * 32 + fk);
      }
#pragma unroll
      for (int m = 0; m < 4; ++m)
#pragma unroll
        for (int n = 0; n < 2; ++n) {
          accH[m][n] = __builtin_amdgcn_mfma_f32_16x16x32_bf16(af[m], bh[n], accH[m][n], 0, 0, 0);
          accL[m][n] = __builtin_amdgcn_mfma_f32_16x16x32_bf16(af[m], bl[n], accL[m][n], 0, 0, 0);
        }
    }
    __syncthreads();  // drains next-tile loads (vmcnt 0) + barrier
    cur ^= 1;
  }

  float* Mb = M + ((size_t)b * CC + by * 128) * CC + bx * 128;
  int orow = wr + (lane >> 4) * 4;
  int ocol = wc + (lane & 15);
#pragma unroll
  for (int m = 0; m < 4; ++m)
#pragma unroll
    for (int n = 0; n < 2; ++n)
#pragma unroll
      for (int q = 0; q < 4; ++q)
        Mb[(size_t)(orow + m * 16 + q) * CC + ocol + n * 16] =
            0.5f * accH[m][n][q] + accL[m][n][q];
}

// ---------- Kernel 3: e = M + M^T; dual softmax; blend -> att (bf16) -------
// XCD-chunked to match gemm1 (M is L2-warm on the producing XCD).
__global__ __launch_bounds__(256) void k_att(const float* __restrict__ M,
                                             const float* __restrict__ mu,
                                             const float* __restrict__ beta_p,
                                             u16* __restrict__ att) {
  __shared__ float pt[32][513];  // [c_local][d] column panel of M
  int lid = blockIdx.x;                  // 0..255
  int sw = (lid & 7) * 32 + (lid >> 3);  // same batch->XCD map as gemm1
  int b = sw >> 4;
  int c0 = (sw & 15) * 32;
  int t = threadIdx.x;
  const float* Mb = M + (size_t)b * CC * CC;

  // stage M[0:512, c0:c0+32] transposed into pt
  int cb = (t & 7) * 4;
  for (int d = t >> 3; d < CC; d += 32) {
    float4 v = *(const float4*)&Mb[(size_t)d * CC + c0 + cb];
    pt[cb + 0][d] = v.x;
    pt[cb + 1][d] = v.y;
    pt[cb + 2][d] = v.z;
    pt[cb + 3][d] = v.w;
  }
  __syncthreads();

  int lane = t & 63, w = t >> 6;
  const float* mub = mu + b * CC;
  float bta = *beta_p;

  for (int i = 0; i < 8; ++i) {
    int cl = w * 8 + i;  // 0..31
    int c = c0 + cl;
    const float* r0 = Mb + (size_t)c * CC;
    float muc = mub[c];

    float e[8], mud[8];
#pragma unroll
    for (int j = 0; j < 8; ++j) {
      int d = lane + j * 64;
      e[j] = r0[d] + pt[cl][d];  // M[c,d] + M[d,c]
      mud[j] = mub[d];
    }
    // softmax(energy_new) == exp(emin - e) / sum
    float emin = fminf(fminf(fminf(e[0], e[1]), fminf(e[2], e[3])),
                       fminf(fminf(e[4], e[5]), fminf(e[6], e[7])));
    emin = wredMin(emin);
    float pe[8], sum_e = 0.f;
#pragma unroll
    for (int j = 0; j < 8; ++j) { pe[j] = __expf(emin - e[j]); sum_e += pe[j]; }
    sum_e = wredSum(sum_e);

    // sigma = (e - N*muc*mud) * (1/(N*sqrt(N)))
    float sg[8];
#pragma unroll
    for (int j = 0; j < 8; ++j)
      sg[j] = (e[j] - (float)NN * muc * mud[j]) * (1.0f / 32768.0f);
    float smax = fmaxf(fmaxf(fmaxf(sg[0], sg[1]), fmaxf(sg[2], sg[3])),
                       fmaxf(fmaxf(sg[4], sg[5]), fmaxf(sg[6], sg[7])));
    smax = wredMax(smax);
    float ps[8], sum_s = 0.f;
#pragma unroll
    for (int j = 0; j < 8; ++j) { ps[j] = __expf(sg[j] - smax); sum_s += ps[j]; }
    sum_s = wredSum(sum_s);

    float we = (1.0f - bta) / sum_e;
    float wsc = bta / sum_s;
    u16* arow = att + ((size_t)b * CC + c) * CC;
#pragma unroll
    for (int j = 0; j < 8; ++j)
      arow[lane + j * 64] = f2bf(ps[j] * wsc + pe[j] * we);
  }
}

// ---------- Kernel 4: out = gamma * (att @ X) + x --------------------------
// NT GEMM: out[c,n] = sum_d att[c,d] * xt[n,d]; 2-phase dbuf pipeline.
__global__ __launch_bounds__(256, 2) void k_gemm2(const u16* __restrict__ att,
                                                  const u16* __restrict__ xt,
                                                  const float* __restrict__ x,
                                                  const float* __restrict__ gamma_p,
                                                  float* __restrict__ out) {
  int lid = blockIdx.x;                  // 0..511
  int sw = (lid & 7) * 64 + (lid >> 3);  // XCD chunking: 2 batches/XCD
  int b = sw >> 5;
  int r = sw & 31;
  int by = r >> 3;  // c tile (0..3)
  int bx = r & 7;   // n tile (0..7)

  __shared__ u16 lds[2 * 16384];  // per buf: A[128*64]@0, B[128*64]@8192
  int t = threadIdx.x;
  int lane = t & 63, w = t >> 6;
  int wr = (w >> 1) * 64, wc = (w & 1) * 64;
  int fr = lane & 15, fk = (lane >> 4) * 8;

  const u16* Ab = att + ((size_t)b * CC + by * 128) * CC;
  const u16* Bb = xt + ((size_t)b * NN + bx * 128) * CC;

  f32x4 acc[4][4];
#pragma unroll
  for (int m = 0; m < 4; ++m)
#pragma unroll
    for (int n = 0; n < 4; ++n) acc[m][n] = (f32x4)(0.0f);

  stageT<128, 256>(lds, Ab, CC, t);
  stageT<128, 256>(lds + 8192, Bb, CC, t);
  __syncthreads();

  int cur = 0;
  for (int ks = 0; ks < CC; ks += 64) {
    if (ks + 64 < CC) {
      u16* nb = lds + (cur ^ 1) * 16384;
      stageT<128, 256>(nb, Ab + ks + 64, CC, t);
      stageT<128, 256>(nb + 8192, Bb + ks + 64, CC, t);
    }
    const u16* cb = lds + cur * 16384;
#pragma unroll
    for (int kk = 0; kk < 2; ++kk) {
      bf16x8 af[4], bg[4];
#pragma unroll
      for (int m = 0; m < 4; ++m) af[m] = ldsfrag(cb, wr + m * 16 + fr, kk * 32 + fk);
#pragma unroll
      for (int n = 0; n < 4; ++n) bg[n] = ldsfrag(cb + 8192, wc + n * 16 + fr, kk * 32 + fk);
#pragma unroll
      for (int m = 0; m < 4; ++m)
#pragma unroll
        for (int n = 0; n < 4; ++n)
          acc[m][n] = __builtin_amdgcn_mfma_f32_16x16x32_bf16(af[m], bg[n], acc[m][n], 0, 0, 0);
    }
    __syncthreads();
    cur ^= 1;
  }

  float g = *gamma_p;
  const float* xb = x + ((size_t)b * CC + by * 128) * NN + bx * 128;
  float* ob = out + ((size_t)b * CC + by * 128) * NN + bx * 128;
  int orow = wr + (lane >> 4) * 4;
  int ocol = wc + (lane & 15);
#pragma unroll
  for (int m = 0; m < 4; ++m)
#pragma unroll
    for (int n = 0; n < 4; ++n)
#pragma unroll
      for (int q = 0; q < 4; ++q) {
        size_t rr = (size_t)(orow + m * 16 + q) * NN + ocol + n * 16;
        ob[rr] = g * acc[m][n][q] + xb[rr];
      }
}

extern "C" void kernel_launch(void* const* d_in, const int* in_sizes, int n_in,
                              void* d_out, int out_size, void* d_ws, size_t ws_size,
                              hipStream_t stream) {
  const float* x = (const float*)d_in[0];
  const float* gamma = (const float*)d_in[1];
  const float* beta = (const float*)d_in[2];
  float* out = (float*)d_out;

  constexpr size_t BCN = (size_t)BB * CC * NN;  // 8,388,608
  constexpr size_t BCC = (size_t)BB * CC * CC;  // 4,194,304
  u16* xhi = (u16*)d_ws;             // 16.78 MB (dead after k_gemm1 -> att)
  u16* xlo = xhi + BCN;              // 16.78 MB
  u16* xt = xlo + BCN;               // 16.78 MB
  float* mu = (float*)(xt + BCN);    // 32 KB
  float* M = mu + (size_t)BB * CC;   // 16.78 MB
  u16* att = xhi;                    // alias: xhi dead after k_gemm1
  // peak ws use ~= 67.2 MB

  k_prepT<<<256, 256, 0, stream>>>(x, xhi, xlo, xt, mu);
  k_gemm1<<<256, 512, 0, stream>>>(xhi, xlo, M);
  k_att<<<256, 256, 0, stream>>>(M, mu, beta, att);
  k_gemm2<<<512, 256, 0, stream>>>(att, xt, x, gamma, out);
}